// Round 2
// baseline (1777.943 us; speedup 1.0000x reference)
//
#include <hip/hip_runtime.h>
#include <math.h>

#define N_NEU 256
#define D_DIM 32
#define KFD   16
#define KN    50
#define B_SZ  512
#define UINF  128
#define GAMMA 0.1f
#define DT    0.05f
#define NSTEP 20

// ---------------------------------------------------------------------------
// Kernel 1: normalized-feature similarity + top-KN selection per row.
// ---------------------------------------------------------------------------
__global__ __launch_bounds__(256) void topk_kernel(const float* __restrict__ features,
                                                   int* __restrict__ idxT,
                                                   float* __restrict__ valsT) {
    __shared__ float fsh[N_NEU][KFD + 1];
    __shared__ float sim_sh[N_NEU];
    const int n = blockIdx.x;
    const int j = threadIdx.x;

    float v[KFD];
    float s = 0.f;
#pragma unroll
    for (int d = 0; d < KFD; ++d) { v[d] = features[j * KFD + d]; s = fmaf(v[d], v[d], s); }
    const float nrm = sqrtf(s);
#pragma unroll
    for (int d = 0; d < KFD; ++d) fsh[j][d] = v[d] / nrm;
    __syncthreads();

    float dot = 0.f;
#pragma unroll
    for (int d = 0; d < KFD; ++d) dot = fmaf(fsh[n][d], fsh[j][d], dot);
    sim_sh[j] = dot;
    __syncthreads();

    if (j < 64) {
        float l0 = sim_sh[j];
        float l1 = sim_sh[j + 64];
        float l2 = sim_sh[j + 128];
        float l3 = sim_sh[j + 192];
        for (int k = 0; k < KN; ++k) {
            float bv = l0; int bi = j;
            if (l1 > bv) { bv = l1; bi = j + 64; }
            if (l2 > bv) { bv = l2; bi = j + 128; }
            if (l3 > bv) { bv = l3; bi = j + 192; }
            for (int off = 32; off > 0; off >>= 1) {
                float ov = __shfl_xor(bv, off, 64);
                int   oi = __shfl_xor(bi, off, 64);
                if (ov > bv || (ov == bv && oi < bi)) { bv = ov; bi = oi; }
            }
            if (j == 0) { valsT[k * N_NEU + n] = bv; idxT[k * N_NEU + n] = bi; }
            if ((bi & 63) == j) {
                const int q = bi >> 6;
                if      (q == 0) l0 = -INFINITY;
                else if (q == 1) l1 = -INFINITY;
                else if (q == 2) l2 = -INFINITY;
                else             l3 = -INFINITY;
            }
        }
    }
}

// ---------------------------------------------------------------------------
// Kernel 2: c[m,d] = u@w_in.T + b_in + bias + sig_b2 (loop-invariant fold).
// ---------------------------------------------------------------------------
__global__ __launch_bounds__(256) void uproj_kernel(const float* __restrict__ u,
                                                    const float* __restrict__ w_in,
                                                    const float* __restrict__ b_in,
                                                    const float* __restrict__ bias,
                                                    const float* __restrict__ sig_b2,
                                                    float* __restrict__ c) {
    __shared__ float ush[8][UINF];
    __shared__ float wsh[D_DIM][UINF + 1];
    const int t = threadIdx.x;
    const long m0 = (long)blockIdx.x * 8;

    for (int i = t; i < D_DIM * UINF; i += 256) wsh[i >> 7][i & 127] = w_in[i];
    const float4 uv = reinterpret_cast<const float4*>(u)[m0 * 32 + t];
    *reinterpret_cast<float4*>(&ush[t >> 5][(t & 31) * 4]) = uv;
    __syncthreads();

    const int ml = t >> 5, d = t & 31;
    float acc = 0.f;
#pragma unroll 8
    for (int k = 0; k < UINF; ++k) acc = fmaf(ush[ml][k], wsh[d][k], acc);

    const long m = m0 + ml;
    const int  nn = (int)(m & (N_NEU - 1));
    c[m * D_DIM + d] = acc + b_in[d] + bias[nn * D_DIM + d] + sig_b2[d];
}

// ---------------------------------------------------------------------------
// Kernel 3: 20-step recurrence. 256 blocks x 512 threads (2 batches/block,
// 1 thread per neuron). State x[32] + folded-constant ccdt[32] in registers.
// __launch_bounds__(512, 1): 256-VGPR budget — round-1's (512,2) capped at
// 128 VGPR and spilled the state arrays -> 5.4 GB scratch traffic, 1520 us.
// Grid is 1 block/CU regardless, so the cap bought nothing.
// ---------------------------------------------------------------------------
__global__ __launch_bounds__(512, 1) void steps_kernel(const float* __restrict__ c,
                                                       const int* __restrict__ idxT,
                                                       const float* __restrict__ valsT,
                                                       const float* __restrict__ sig_w1,
                                                       const float* __restrict__ sig_b1,
                                                       const float* __restrict__ sig_w2,
                                                       float* __restrict__ out) {
    __shared__ float a_sh[2][N_NEU];
    __shared__ float vals_sh[KN * N_NEU];      // 50 KiB
    __shared__ float sw1[16], sb1[16];
    __shared__ float sw2t[16 * 32];            // [j][d], pre-scaled by DT

    const int t  = threadIdx.x;
    const int bl = t >> 8;
    const int n  = t & (N_NEU - 1);
    const int b  = blockIdx.x * 2 + bl;

    for (int i = t; i < KN * N_NEU; i += 512) vals_sh[i] = valsT[i];
    if (t < 16) { sw1[t] = sig_w1[t]; sb1[t] = sig_b1[t]; }
    sw2t[(t & 15) * 32 + (t >> 4)] = DT * sig_w2[t];   // fold DT into w2

    unsigned int idxp[13];
#pragma unroll
    for (int w = 0; w < 13; ++w) idxp[w] = 0u;
#pragma unroll
    for (int k = 0; k < KN; ++k) {
        const unsigned int ii = (unsigned int)idxT[k * N_NEU + n];
        idxp[k >> 2] |= ii << ((k & 3) * 8);
    }

    float x[D_DIM], ccdt[D_DIM];
    const float4* cp4 = reinterpret_cast<const float4*>(c + ((size_t)b * N_NEU + n) * D_DIM);
#pragma unroll
    for (int i = 0; i < 8; ++i) {
        const float4 cv = cp4[i];
        ccdt[4 * i + 0] = DT * cv.x; ccdt[4 * i + 1] = DT * cv.y;
        ccdt[4 * i + 2] = DT * cv.z; ccdt[4 * i + 3] = DT * cv.w;
    }
#pragma unroll
    for (int d = 0; d < D_DIM; ++d) x[d] = 0.f;
    __syncthreads();

    const float K1 = 1.0f - DT * GAMMA;   // 0.995

    for (int s = 0; s < NSTEP; ++s) {
        float nrm2 = 1e-12f;
#pragma unroll
        for (int d = 0; d < D_DIM; ++d) nrm2 = fmaf(x[d], x[d], nrm2);
        const float a = tanhf(sqrtf(nrm2));

        __syncthreads();            // previous step's gathers done
        a_sh[bl][n] = a;
        __syncthreads();            // a visible

        float syn = 0.f;
#pragma unroll
        for (int k = 0; k < KN; ++k) {
            const int ii = (int)((idxp[k >> 2] >> ((k & 3) * 8)) & 255u);
            syn = fmaf(a_sh[bl][ii], vals_sh[k * N_NEU + n], syn);
        }

        // x <- K1*x + DT*cc  (then += DT*g_j*w2 below; DT folded into sw2t)
#pragma unroll
        for (int d = 0; d < D_DIM; ++d) x[d] = fmaf(K1, x[d], ccdt[d]);

#pragma unroll
        for (int j = 0; j < 16; ++j) {
            const float hj = fmaf(syn, sw1[j], sb1[j]);
            const float g  = 0.5f * hj * (1.0f + erff(hj * 0.70710678118654752f));
#pragma unroll
            for (int d = 0; d < D_DIM; ++d) x[d] = fmaf(g, sw2t[j * 32 + d], x[d]);
        }
    }

    float4* op4 = reinterpret_cast<float4*>(out + ((size_t)b * N_NEU + n) * D_DIM);
#pragma unroll
    for (int i = 0; i < 8; ++i)
        op4[i] = make_float4(x[4 * i + 0], x[4 * i + 1], x[4 * i + 2], x[4 * i + 3]);
}

extern "C" void kernel_launch(void* const* d_in, const int* in_sizes, int n_in,
                              void* d_out, int out_size, void* d_ws, size_t ws_size,
                              hipStream_t stream) {
    const float* u        = (const float*)d_in[0];
    const float* features = (const float*)d_in[1];
    const float* bias     = (const float*)d_in[2];
    const float* w_in     = (const float*)d_in[3];
    const float* b_in     = (const float*)d_in[4];
    const float* sig_w1   = (const float*)d_in[5];
    const float* sig_b1   = (const float*)d_in[6];
    const float* sig_w2   = (const float*)d_in[7];
    const float* sig_b2   = (const float*)d_in[8];
    float* out = (float*)d_out;

    char*  ws    = (char*)d_ws;
    int*   idxT  = (int*)ws;                    // 51200 B
    float* valsT = (float*)(ws + 51200);        // 51200 B
    float* c     = (float*)(ws + 102400);       // 16 MiB

    hipLaunchKernelGGL(topk_kernel, dim3(N_NEU), dim3(256), 0, stream,
                       features, idxT, valsT);
    hipLaunchKernelGGL(uproj_kernel, dim3(B_SZ * N_NEU / 8), dim3(256), 0, stream,
                       u, w_in, b_in, bias, sig_b2, c);
    hipLaunchKernelGGL(steps_kernel, dim3(B_SZ / 2), dim3(512), 0, stream,
                       c, idxT, valsT, sig_w1, sig_b1, sig_w2, out);
}

// Round 3
// 229.095 us; speedup vs baseline: 7.7607x; 7.7607x over previous
//
#include <hip/hip_runtime.h>
#include <math.h>

#define N_NEU 256
#define D_DIM 32
#define KFD   16
#define KN    50
#define B_SZ  512
#define UINF  128
#define GAMMA 0.1f
#define DT    0.05f
#define NSTEP 20

// ---------------------------------------------------------------------------
// Kernel 1: normalized-feature similarity + top-KN selection per row.
// (unchanged from round 1 — works, ~3 us)
// ---------------------------------------------------------------------------
__global__ __launch_bounds__(256) void topk_kernel(const float* __restrict__ features,
                                                   int* __restrict__ idxT,
                                                   float* __restrict__ valsT) {
    __shared__ float fsh[N_NEU][KFD + 1];
    __shared__ float sim_sh[N_NEU];
    const int n = blockIdx.x;
    const int j = threadIdx.x;

    float v[KFD];
    float s = 0.f;
#pragma unroll
    for (int d = 0; d < KFD; ++d) { v[d] = features[j * KFD + d]; s = fmaf(v[d], v[d], s); }
    const float nrm = sqrtf(s);
#pragma unroll
    for (int d = 0; d < KFD; ++d) fsh[j][d] = v[d] / nrm;
    __syncthreads();

    float dot = 0.f;
#pragma unroll
    for (int d = 0; d < KFD; ++d) dot = fmaf(fsh[n][d], fsh[j][d], dot);
    sim_sh[j] = dot;
    __syncthreads();

    if (j < 64) {
        float l0 = sim_sh[j];
        float l1 = sim_sh[j + 64];
        float l2 = sim_sh[j + 128];
        float l3 = sim_sh[j + 192];
        for (int k = 0; k < KN; ++k) {
            float bv = l0; int bi = j;
            if (l1 > bv) { bv = l1; bi = j + 64; }
            if (l2 > bv) { bv = l2; bi = j + 128; }
            if (l3 > bv) { bv = l3; bi = j + 192; }
            for (int off = 32; off > 0; off >>= 1) {
                float ov = __shfl_xor(bv, off, 64);
                int   oi = __shfl_xor(bi, off, 64);
                if (ov > bv || (ov == bv && oi < bi)) { bv = ov; bi = oi; }
            }
            if (j == 0) { valsT[k * N_NEU + n] = bv; idxT[k * N_NEU + n] = bi; }
            if ((bi & 63) == j) {
                const int q = bi >> 6;
                if      (q == 0) l0 = -INFINITY;
                else if (q == 1) l1 = -INFINITY;
                else if (q == 2) l2 = -INFINITY;
                else             l3 = -INFINITY;
            }
        }
    }
}

// ---------------------------------------------------------------------------
// Kernel 2: cdt[m,d] = DT * (u@w_in.T + b_in + bias + sig_b2)  (DT prefolded).
// Block 0 additionally writes w2dt[j*32+d] = DT * sig_w2[d,j] (transposed,
// DT-folded) so steps_kernel can consume the weights via uniform scalar loads.
// ---------------------------------------------------------------------------
__global__ __launch_bounds__(256) void uproj_kernel(const float* __restrict__ u,
                                                    const float* __restrict__ w_in,
                                                    const float* __restrict__ b_in,
                                                    const float* __restrict__ bias,
                                                    const float* __restrict__ sig_b2,
                                                    const float* __restrict__ sig_w2,
                                                    float* __restrict__ cdt,
                                                    float* __restrict__ w2dt) {
    __shared__ float ush[8][UINF];
    __shared__ float wsh[D_DIM][UINF + 1];
    const int t = threadIdx.x;
    const long m0 = (long)blockIdx.x * 8;

    if (blockIdx.x == 0) {
#pragma unroll
        for (int i = t; i < 16 * D_DIM; i += 256) {
            const int j = i >> 5, d = i & 31;
            w2dt[i] = DT * sig_w2[d * 16 + j];
        }
    }

    for (int i = t; i < D_DIM * UINF; i += 256) wsh[i >> 7][i & 127] = w_in[i];
    const float4 uv = reinterpret_cast<const float4*>(u)[m0 * 32 + t];
    *reinterpret_cast<float4*>(&ush[t >> 5][(t & 31) * 4]) = uv;
    __syncthreads();

    const int ml = t >> 5, d = t & 31;
    float acc = 0.f;
#pragma unroll 8
    for (int k = 0; k < UINF; ++k) acc = fmaf(ush[ml][k], wsh[d][k], acc);

    const long m = m0 + ml;
    const int  nn = (int)(m & (N_NEU - 1));
    cdt[m * D_DIM + d] = DT * (acc + b_in[d] + bias[nn * D_DIM + d] + sig_b2[d]);
}

// ---------------------------------------------------------------------------
// Kernel 3: 20-step recurrence. Grid 512 x 256 threads: 1 batch per block,
// 1 thread per neuron, 2 blocks/CU.
// Register-pressure design (rounds 1-2 spilled x[] -> 5.3 GB scratch traffic):
//  - persistent VGPR state is only x[32] + packed idx[13]  (~45 regs)
//  - sigma-MLP weights w2dt / sig_w1 / sig_b1 are read with wave-UNIFORM
//    addresses from read-only global -> s_load + SGPR-operand v_fmac
//    (no VGPR tuples, no LDS traffic for weights)
//  - cdt re-read from global every step (L2-resident) instead of 32 registers
// ---------------------------------------------------------------------------
__global__ __launch_bounds__(256) void steps_kernel(const float* __restrict__ cdt,
                                                    const int* __restrict__ idxT,
                                                    const float* __restrict__ valsT,
                                                    const float* __restrict__ sig_w1,
                                                    const float* __restrict__ sig_b1,
                                                    const float* __restrict__ w2dt,
                                                    float* __restrict__ out) {
    __shared__ float a_sh[N_NEU];
    __shared__ float vals_sh[KN * N_NEU];      // 50 KiB

    const int n = threadIdx.x;
    const int b = blockIdx.x;

    for (int i = n; i < KN * N_NEU; i += 256) vals_sh[i] = valsT[i];

    // pack the 50 neighbor indices (each < 256) into 13 u32 registers
    unsigned int idxp[13];
#pragma unroll
    for (int w = 0; w < 13; ++w) idxp[w] = 0u;
#pragma unroll
    for (int k = 0; k < KN; ++k) {
        const unsigned int ii = (unsigned int)idxT[k * N_NEU + n];
        idxp[k >> 2] |= ii << ((k & 3) * 8);
    }

    float x[D_DIM];
#pragma unroll
    for (int d = 0; d < D_DIM; ++d) x[d] = 0.f;

    const float4* cp4 = reinterpret_cast<const float4*>(cdt + ((size_t)b * N_NEU + n) * D_DIM);
    const float K1 = 1.0f - DT * GAMMA;   // 0.995

    for (int s = 0; s < NSTEP; ++s) {
        float nrm2 = 1e-12f;
#pragma unroll
        for (int d = 0; d < D_DIM; ++d) nrm2 = fmaf(x[d], x[d], nrm2);
        const float a = tanhf(sqrtf(nrm2));

        __syncthreads();            // prev-step gathers done (iter 0: staging done)
        a_sh[n] = a;
        __syncthreads();            // a visible

        float syn = 0.f;
#pragma unroll
        for (int k = 0; k < KN; ++k) {
            const int ii = (int)((idxp[k >> 2] >> ((k & 3) * 8)) & 255u);
            syn = fmaf(a_sh[ii], vals_sh[k * N_NEU + n], syn);
        }

        // x <- K1*x + cdt   (cdt already DT-scaled, L2-hot re-read)
#pragma unroll
        for (int i = 0; i < 8; ++i) {
            const float4 cv = cp4[i];
            x[4 * i + 0] = fmaf(K1, x[4 * i + 0], cv.x);
            x[4 * i + 1] = fmaf(K1, x[4 * i + 1], cv.y);
            x[4 * i + 2] = fmaf(K1, x[4 * i + 2], cv.z);
            x[4 * i + 3] = fmaf(K1, x[4 * i + 3], cv.w);
        }

        // sigma MLP: weights via uniform (scalar) loads, DT folded into w2dt
#pragma unroll
        for (int j = 0; j < 16; ++j) {
            const float hj = fmaf(syn, sig_w1[j], sig_b1[j]);
            const float g  = 0.5f * hj * (1.0f + erff(hj * 0.70710678118654752f));
#pragma unroll
            for (int d = 0; d < D_DIM; ++d) x[d] = fmaf(g, w2dt[j * 32 + d], x[d]);
        }
    }

    float4* op4 = reinterpret_cast<float4*>(out + ((size_t)b * N_NEU + n) * D_DIM);
#pragma unroll
    for (int i = 0; i < 8; ++i)
        op4[i] = make_float4(x[4 * i + 0], x[4 * i + 1], x[4 * i + 2], x[4 * i + 3]);
}

extern "C" void kernel_launch(void* const* d_in, const int* in_sizes, int n_in,
                              void* d_out, int out_size, void* d_ws, size_t ws_size,
                              hipStream_t stream) {
    const float* u        = (const float*)d_in[0];
    const float* features = (const float*)d_in[1];
    const float* bias     = (const float*)d_in[2];
    const float* w_in     = (const float*)d_in[3];
    const float* b_in     = (const float*)d_in[4];
    const float* sig_w1   = (const float*)d_in[5];
    const float* sig_b1   = (const float*)d_in[6];
    const float* sig_w2   = (const float*)d_in[7];
    const float* sig_b2   = (const float*)d_in[8];
    float* out = (float*)d_out;

    char*  ws    = (char*)d_ws;
    int*   idxT  = (int*)ws;                    // 51200 B
    float* valsT = (float*)(ws + 51200);        // 51200 B
    float* w2dt  = (float*)(ws + 102400);       // 2048 B
    float* cdt   = (float*)(ws + 104448);       // 16 MiB

    hipLaunchKernelGGL(topk_kernel, dim3(N_NEU), dim3(256), 0, stream,
                       features, idxT, valsT);
    hipLaunchKernelGGL(uproj_kernel, dim3(B_SZ * N_NEU / 8), dim3(256), 0, stream,
                       u, w_in, b_in, bias, sig_b2, sig_w2, cdt, w2dt);
    hipLaunchKernelGGL(steps_kernel, dim3(B_SZ), dim3(256), 0, stream,
                       cdt, idxT, valsT, sig_w1, sig_b1, w2dt, out);
}

// Round 4
// 168.465 us; speedup vs baseline: 10.5538x; 1.3599x over previous
//
#include <hip/hip_runtime.h>
#include <math.h>

#define N_NEU 256
#define D_DIM 32
#define KFD   16
#define KN    50
#define B_SZ  512
#define UINF  128
#define GAMMA 0.1f
#define DT    0.05f
#define NSTEP 20

#define TBL_K   4096
#define TBL_LO  (-64.0f)
#define TBL_IDL 32.0f          // 1/Delta ; Delta = 1/32, range [-64, +64)

__device__ __forceinline__ unsigned short f2bf(float f) {
    unsigned u = __float_as_uint(f);
    u += 0x7FFFu + ((u >> 16) & 1u);     // round-to-nearest-even
    return (unsigned short)(u >> 16);
}
__device__ __forceinline__ float bf_lo(unsigned q) { return __uint_as_float(q << 16); }
__device__ __forceinline__ float bf_hi(unsigned q) { return __uint_as_float(q & 0xFFFF0000u); }

// ---------------------------------------------------------------------------
// Kernel 1: normalized-feature similarity + top-KN per row.
// vals written in PAIRED layout vals2T[(k/2)*512 + n*2 + (k&1)] so steps can
// ds_read_b64 two neighbors at once.
// ---------------------------------------------------------------------------
__global__ __launch_bounds__(256) void topk_kernel(const float* __restrict__ features,
                                                   int* __restrict__ idxT,
                                                   float* __restrict__ vals2T) {
    __shared__ float fsh[N_NEU][KFD + 1];
    __shared__ float sim_sh[N_NEU];
    const int n = blockIdx.x;
    const int j = threadIdx.x;

    float v[KFD];
    float s = 0.f;
#pragma unroll
    for (int d = 0; d < KFD; ++d) { v[d] = features[j * KFD + d]; s = fmaf(v[d], v[d], s); }
    const float nrm = sqrtf(s);
#pragma unroll
    for (int d = 0; d < KFD; ++d) fsh[j][d] = v[d] / nrm;
    __syncthreads();

    float dot = 0.f;
#pragma unroll
    for (int d = 0; d < KFD; ++d) dot = fmaf(fsh[n][d], fsh[j][d], dot);
    sim_sh[j] = dot;
    __syncthreads();

    if (j < 64) {
        float l0 = sim_sh[j];
        float l1 = sim_sh[j + 64];
        float l2 = sim_sh[j + 128];
        float l3 = sim_sh[j + 192];
        for (int k = 0; k < KN; ++k) {
            float bv = l0; int bi = j;
            if (l1 > bv) { bv = l1; bi = j + 64; }
            if (l2 > bv) { bv = l2; bi = j + 128; }
            if (l3 > bv) { bv = l3; bi = j + 192; }
            for (int off = 32; off > 0; off >>= 1) {
                float ov = __shfl_xor(bv, off, 64);
                int   oi = __shfl_xor(bi, off, 64);
                if (ov > bv || (ov == bv && oi < bi)) { bv = ov; bi = oi; }
            }
            if (j == 0) {
                vals2T[(k >> 1) * (2 * N_NEU) + n * 2 + (k & 1)] = bv;
                idxT[k * N_NEU + n] = bi;
            }
            if ((bi & 63) == j) {
                const int q = bi >> 6;
                if      (q == 0) l0 = -INFINITY;
                else if (q == 1) l1 = -INFINITY;
                else if (q == 2) l2 = -INFINITY;
                else             l3 = -INFINITY;
            }
        }
    }
}

// ---------------------------------------------------------------------------
// Kernel 2: tabulate G_d(s) = DT * sum_j gelu(s*w1_j + b1_j) * w2[d,j]
// as piecewise-linear: entry u32 = bf16(G_d(s_k)) | bf16(G_d(s_{k+1})-G_d(s_k))<<16.
// One row per knot = 32 u32 = 128 B. Linear extrapolation past the ends is
// exact asymptotically (gelu -> linear), so no clamping error.
// ---------------------------------------------------------------------------
__global__ __launch_bounds__(256) void mlp_table_kernel(const float* __restrict__ sig_w1,
                                                        const float* __restrict__ sig_b1,
                                                        const float* __restrict__ sig_w2,
                                                        unsigned int* __restrict__ tbl) {
    const int gid = blockIdx.x * 256 + threadIdx.x;   // gid = k*32 + d
    const int k = gid >> 5, d = gid & 31;
    const float s0 = TBL_LO + (float)k / TBL_IDL;
    const float s1 = s0 + 1.0f / TBL_IDL;
    float g0 = 0.f, g1 = 0.f;
#pragma unroll
    for (int j = 0; j < 16; ++j) {
        const float w1 = sig_w1[j], b1 = sig_b1[j], w2 = sig_w2[d * 16 + j];
        const float h0 = fmaf(s0, w1, b1);
        const float h1 = fmaf(s1, w1, b1);
        const float e0 = 0.5f * h0 * (1.0f + erff(h0 * 0.70710678118654752f));
        const float e1 = 0.5f * h1 * (1.0f + erff(h1 * 0.70710678118654752f));
        g0 = fmaf(e0, w2, g0);
        g1 = fmaf(e1, w2, g1);
    }
    g0 *= DT; g1 *= DT;
    tbl[gid] = (unsigned int)f2bf(g0) | ((unsigned int)f2bf(g1 - g0) << 16);
}

// ---------------------------------------------------------------------------
// Kernel 3: cdt[m,d] = DT * (u@w_in.T + b_in + bias + sig_b2).
// ---------------------------------------------------------------------------
__global__ __launch_bounds__(256) void uproj_kernel(const float* __restrict__ u,
                                                    const float* __restrict__ w_in,
                                                    const float* __restrict__ b_in,
                                                    const float* __restrict__ bias,
                                                    const float* __restrict__ sig_b2,
                                                    float* __restrict__ cdt) {
    __shared__ float ush[8][UINF];
    __shared__ float wsh[D_DIM][UINF + 1];
    const int t = threadIdx.x;
    const long m0 = (long)blockIdx.x * 8;

    for (int i = t; i < D_DIM * UINF; i += 256) wsh[i >> 7][i & 127] = w_in[i];
    const float4 uv = reinterpret_cast<const float4*>(u)[m0 * 32 + t];
    *reinterpret_cast<float4*>(&ush[t >> 5][(t & 31) * 4]) = uv;
    __syncthreads();

    const int ml = t >> 5, d = t & 31;
    float acc = 0.f;
#pragma unroll 8
    for (int k = 0; k < UINF; ++k) acc = fmaf(ush[ml][k], wsh[d][k], acc);

    const long m = m0 + ml;
    const int  nn = (int)(m & (N_NEU - 1));
    cdt[m * D_DIM + d] = DT * (acc + b_in[d] + bias[nn * D_DIM + d] + sig_b2[d]);
}

// ---------------------------------------------------------------------------
// Kernel 4: 20-step recurrence. Grid 512 x 256: 1 batch/block, 1 thread/neuron.
// Persistent VGPR state: x[32] + packed idx[13] (~50 regs, no spill).
// Sigma-MLP replaced by table lerp: 8 uint4 L2 loads + ~130 VALU per step
// (was 512 FMA + 16 erff). vals read as float2 pairs (ds_read_b64, 2-way
// bank alias = free). cdt re-read from L2 each step to keep pressure low.
// ---------------------------------------------------------------------------
__global__ __launch_bounds__(256) void steps_kernel(const float* __restrict__ cdt,
                                                    const int* __restrict__ idxT,
                                                    const float* __restrict__ vals2T,
                                                    const unsigned int* __restrict__ tbl,
                                                    float* __restrict__ out) {
    __shared__ float  a_sh[N_NEU];
    __shared__ float2 vals2_sh[(KN / 2) * N_NEU];   // 25*256*8 = 51200 B

    const int n = threadIdx.x;
    const int b = blockIdx.x;

    const float2* v2g = reinterpret_cast<const float2*>(vals2T);
    for (int i = n; i < (KN / 2) * N_NEU; i += 256) vals2_sh[i] = v2g[i];

    unsigned int idxp[13];
#pragma unroll
    for (int w = 0; w < 13; ++w) idxp[w] = 0u;
#pragma unroll
    for (int k = 0; k < KN; ++k) {
        const unsigned int ii = (unsigned int)idxT[k * N_NEU + n];
        idxp[k >> 2] |= ii << ((k & 3) * 8);
    }

    float x[D_DIM];
#pragma unroll
    for (int d = 0; d < D_DIM; ++d) x[d] = 0.f;

    const float4* cp4 = reinterpret_cast<const float4*>(cdt + ((size_t)b * N_NEU + n) * D_DIM);
    const float K1 = 1.0f - DT * GAMMA;   // 0.995

    for (int s = 0; s < NSTEP; ++s) {
        float nrm2 = 1e-12f;
#pragma unroll
        for (int d = 0; d < D_DIM; ++d) nrm2 = fmaf(x[d], x[d], nrm2);
        const float a = tanhf(sqrtf(nrm2));

        __syncthreads();            // prev-step gathers done (iter 0: staging done)
        a_sh[n] = a;
        __syncthreads();            // a visible

        float syn = 0.f;
#pragma unroll
        for (int k2 = 0; k2 < KN / 2; ++k2) {
            const float2 vv = vals2_sh[k2 * N_NEU + n];
            const int k0 = 2 * k2, k1 = 2 * k2 + 1;
            const int i0 = (int)((idxp[k0 >> 2] >> ((k0 & 3) * 8)) & 255u);
            const int i1 = (int)((idxp[k1 >> 2] >> ((k1 & 3) * 8)) & 255u);
            syn = fmaf(a_sh[i0], vv.x, syn);
            syn = fmaf(a_sh[i1], vv.y, syn);
        }

        // x <- K1*x + cdt (cdt pre-scaled by DT, L2-hot re-read)
#pragma unroll
        for (int i = 0; i < 8; ++i) {
            const float4 cv = cp4[i];
            x[4 * i + 0] = fmaf(K1, x[4 * i + 0], cv.x);
            x[4 * i + 1] = fmaf(K1, x[4 * i + 1], cv.y);
            x[4 * i + 2] = fmaf(K1, x[4 * i + 2], cv.z);
            x[4 * i + 3] = fmaf(K1, x[4 * i + 3], cv.w);
        }

        // sigma MLP via table lerp: x[d] += val_d(i) + t * delta_d(i)
        const float uu = fmaf(syn, TBL_IDL, -TBL_LO * TBL_IDL);
        int i = (int)floorf(uu);
        i = (i < 0) ? 0 : (i > TBL_K - 2 ? TBL_K - 2 : i);
        const float t = uu - (float)i;
        const uint4* rp = reinterpret_cast<const uint4*>(tbl + (size_t)i * 32);
#pragma unroll 2
        for (int c = 0; c < 8; ++c) {
            const uint4 q = rp[c];
            x[4 * c + 0] = fmaf(t, bf_hi(q.x), x[4 * c + 0] + bf_lo(q.x));
            x[4 * c + 1] = fmaf(t, bf_hi(q.y), x[4 * c + 1] + bf_lo(q.y));
            x[4 * c + 2] = fmaf(t, bf_hi(q.z), x[4 * c + 2] + bf_lo(q.z));
            x[4 * c + 3] = fmaf(t, bf_hi(q.w), x[4 * c + 3] + bf_lo(q.w));
        }
    }

    float4* op4 = reinterpret_cast<float4*>(out + ((size_t)b * N_NEU + n) * D_DIM);
#pragma unroll
    for (int i = 0; i < 8; ++i)
        op4[i] = make_float4(x[4 * i + 0], x[4 * i + 1], x[4 * i + 2], x[4 * i + 3]);
}

extern "C" void kernel_launch(void* const* d_in, const int* in_sizes, int n_in,
                              void* d_out, int out_size, void* d_ws, size_t ws_size,
                              hipStream_t stream) {
    const float* u        = (const float*)d_in[0];
    const float* features = (const float*)d_in[1];
    const float* bias     = (const float*)d_in[2];
    const float* w_in     = (const float*)d_in[3];
    const float* b_in     = (const float*)d_in[4];
    const float* sig_w1   = (const float*)d_in[5];
    const float* sig_b1   = (const float*)d_in[6];
    const float* sig_w2   = (const float*)d_in[7];
    const float* sig_b2   = (const float*)d_in[8];
    float* out = (float*)d_out;

    char*         ws     = (char*)d_ws;
    int*          idxT   = (int*)ws;                      // 51200 B
    float*        vals2T = (float*)(ws + 51200);          // 51200 B
    unsigned int* tbl    = (unsigned int*)(ws + 102400);  // 4096*32*4 = 512 KiB
    float*        cdt    = (float*)(ws + 102400 + 524288);// 16 MiB

    hipLaunchKernelGGL(topk_kernel, dim3(N_NEU), dim3(256), 0, stream,
                       features, idxT, vals2T);
    hipLaunchKernelGGL(mlp_table_kernel, dim3(TBL_K * 32 / 256), dim3(256), 0, stream,
                       sig_w1, sig_b1, sig_w2, tbl);
    hipLaunchKernelGGL(uproj_kernel, dim3(B_SZ * N_NEU / 8), dim3(256), 0, stream,
                       u, w_in, b_in, bias, sig_b2, cdt);
    hipLaunchKernelGGL(steps_kernel, dim3(B_SZ), dim3(256), 0, stream,
                       cdt, idxT, vals2T, tbl, out);
}

// Round 5
// 139.204 us; speedup vs baseline: 12.7722x; 1.2102x over previous
//
#include <hip/hip_runtime.h>
#include <math.h>

#define N_NEU 256
#define D_DIM 32
#define KFD   16
#define KN    50
#define B_SZ  512
#define UINF  128
#define GAMMA 0.1f
#define DT    0.05f
#define NSTEP 20

#define TBL_K   4096
#define TBL_LO  (-64.0f)
#define TBL_IDL 32.0f          // 1/Delta ; Delta = 1/32, range [-64, +64)

typedef __attribute__((ext_vector_type(8))) short bf16x8;
typedef __attribute__((ext_vector_type(4))) float f32x4;

__device__ __forceinline__ unsigned short f2bf(float f) {
    unsigned u = __float_as_uint(f);
    u += 0x7FFFu + ((u >> 16) & 1u);     // round-to-nearest-even
    return (unsigned short)(u >> 16);
}
__device__ __forceinline__ float bf_lo(unsigned q) { return __uint_as_float(q << 16); }
__device__ __forceinline__ float bf_hi(unsigned q) { return __uint_as_float(q & 0xFFFF0000u); }

// ---------------------------------------------------------------------------
// Kernel 1: normalized-feature similarity + top-KN per row (unchanged).
// ---------------------------------------------------------------------------
__global__ __launch_bounds__(256) void topk_kernel(const float* __restrict__ features,
                                                   int* __restrict__ idxT,
                                                   float* __restrict__ vals2T) {
    __shared__ float fsh[N_NEU][KFD + 1];
    __shared__ float sim_sh[N_NEU];
    const int n = blockIdx.x;
    const int j = threadIdx.x;

    float v[KFD];
    float s = 0.f;
#pragma unroll
    for (int d = 0; d < KFD; ++d) { v[d] = features[j * KFD + d]; s = fmaf(v[d], v[d], s); }
    const float nrm = sqrtf(s);
#pragma unroll
    for (int d = 0; d < KFD; ++d) fsh[j][d] = v[d] / nrm;
    __syncthreads();

    float dot = 0.f;
#pragma unroll
    for (int d = 0; d < KFD; ++d) dot = fmaf(fsh[n][d], fsh[j][d], dot);
    sim_sh[j] = dot;
    __syncthreads();

    if (j < 64) {
        float l0 = sim_sh[j];
        float l1 = sim_sh[j + 64];
        float l2 = sim_sh[j + 128];
        float l3 = sim_sh[j + 192];
        for (int k = 0; k < KN; ++k) {
            float bv = l0; int bi = j;
            if (l1 > bv) { bv = l1; bi = j + 64; }
            if (l2 > bv) { bv = l2; bi = j + 128; }
            if (l3 > bv) { bv = l3; bi = j + 192; }
            for (int off = 32; off > 0; off >>= 1) {
                float ov = __shfl_xor(bv, off, 64);
                int   oi = __shfl_xor(bi, off, 64);
                if (ov > bv || (ov == bv && oi < bi)) { bv = ov; bi = oi; }
            }
            if (j == 0) {
                vals2T[(k >> 1) * (2 * N_NEU) + n * 2 + (k & 1)] = bv;
                idxT[k * N_NEU + n] = bi;
            }
            if ((bi & 63) == j) {
                const int q = bi >> 6;
                if      (q == 0) l0 = -INFINITY;
                else if (q == 1) l1 = -INFINITY;
                else if (q == 2) l2 = -INFINITY;
                else             l3 = -INFINITY;
            }
        }
    }
}

// ---------------------------------------------------------------------------
// Kernel 2: piecewise-linear table of G_d(s) (unchanged).
// ---------------------------------------------------------------------------
__global__ __launch_bounds__(256) void mlp_table_kernel(const float* __restrict__ sig_w1,
                                                        const float* __restrict__ sig_b1,
                                                        const float* __restrict__ sig_w2,
                                                        unsigned int* __restrict__ tbl) {
    const int gid = blockIdx.x * 256 + threadIdx.x;   // gid = k*32 + d
    const int k = gid >> 5, d = gid & 31;
    const float s0 = TBL_LO + (float)k / TBL_IDL;
    const float s1 = s0 + 1.0f / TBL_IDL;
    float g0 = 0.f, g1 = 0.f;
#pragma unroll
    for (int j = 0; j < 16; ++j) {
        const float w1 = sig_w1[j], b1 = sig_b1[j], w2 = sig_w2[d * 16 + j];
        const float h0 = fmaf(s0, w1, b1);
        const float h1 = fmaf(s1, w1, b1);
        const float e0 = 0.5f * h0 * (1.0f + erff(h0 * 0.70710678118654752f));
        const float e1 = 0.5f * h1 * (1.0f + erff(h1 * 0.70710678118654752f));
        g0 = fmaf(e0, w2, g0);
        g1 = fmaf(e1, w2, g1);
    }
    g0 *= DT; g1 *= DT;
    tbl[gid] = (unsigned int)f2bf(g0) | ((unsigned int)f2bf(g1 - g0) << 16);
}

// ---------------------------------------------------------------------------
// Kernel 3: uproj via bf16 MFMA.  cdt[m,d] = DT*(u@w_in.T + b_in + bias + sig_b2)
// Round-4's LDS version issued 2 ds_read per FMA (LDS-instruction-bound).
// Here: 1 block = 4 waves, each wave one 16-row m-tile (block = 64 rows).
// A = u rows (f32 -> bf16 RNE inline), B = w_in (col = lane&15 = w_in row).
// K-permutation of A/B fragments cancels in the dot product as long as A and
// B use the same (lane-group, elem)->k convention (they do).
// C/D: col = lane&15, row = (lane>>4)*4 + reg  [m89-verified].
// ---------------------------------------------------------------------------
__global__ __launch_bounds__(256) void uproj_mfma_kernel(const float* __restrict__ u,
                                                         const float* __restrict__ w_in,
                                                         const float* __restrict__ b_in,
                                                         const float* __restrict__ bias,
                                                         const float* __restrict__ sig_b2,
                                                         float* __restrict__ cdt) {
    const int  wave = threadIdx.x >> 6;
    const int  lane = threadIdx.x & 63;
    const long m0   = (long)blockIdx.x * 64 + (long)wave * 16;
    const int  row  = lane & 15;
    const int  kg   = lane >> 4;

    // B fragments: w_in[n][k], n = dt*16 + row, k = kk*32 + kg*8 + e
    bf16x8 bfrag[2][4];
#pragma unroll
    for (int dt_ = 0; dt_ < 2; ++dt_) {
#pragma unroll
        for (int kk = 0; kk < 4; ++kk) {
            const float* wp = w_in + (dt_ * 16 + row) * UINF + kk * 32 + kg * 8;
            bf16x8 f;
#pragma unroll
            for (int e = 0; e < 8; ++e) f[e] = (short)f2bf(wp[e]);
            bfrag[dt_][kk] = f;
        }
    }

    f32x4 acc0 = {0.f, 0.f, 0.f, 0.f};
    f32x4 acc1 = {0.f, 0.f, 0.f, 0.f};
#pragma unroll
    for (int kk = 0; kk < 4; ++kk) {
        const float* up = u + (m0 + row) * UINF + kk * 32 + kg * 8;
        const float4 a0 = *reinterpret_cast<const float4*>(up);
        const float4 a1 = *reinterpret_cast<const float4*>(up + 4);
        bf16x8 af;
        af[0] = (short)f2bf(a0.x); af[1] = (short)f2bf(a0.y);
        af[2] = (short)f2bf(a0.z); af[3] = (short)f2bf(a0.w);
        af[4] = (short)f2bf(a1.x); af[5] = (short)f2bf(a1.y);
        af[6] = (short)f2bf(a1.z); af[7] = (short)f2bf(a1.w);
        acc0 = __builtin_amdgcn_mfma_f32_16x16x32_bf16(af, bfrag[0][kk], acc0, 0, 0, 0);
        acc1 = __builtin_amdgcn_mfma_f32_16x16x32_bf16(af, bfrag[1][kk], acc1, 0, 0, 0);
    }

#pragma unroll
    for (int r = 0; r < 4; ++r) {
        const long m  = m0 + kg * 4 + r;
        const int  nn = (int)(m & (N_NEU - 1));
        const int  d0 = row;
        const int  d1 = 16 + row;
        cdt[m * D_DIM + d0] = DT * (acc0[r] + b_in[d0] + bias[nn * D_DIM + d0] + sig_b2[d0]);
        cdt[m * D_DIM + d1] = DT * (acc1[r] + b_in[d1] + bias[nn * D_DIM + d1] + sig_b2[d1]);
    }
}

// ---------------------------------------------------------------------------
// Kernel 4: 20-step recurrence. Grid 512 x 256: 1 batch/block, 1 thread/neuron.
// vs round 4: ccdt held in registers (VGPR ~120, below the 128 no-spill line),
// ONE barrier per step via double-buffered a_sh (WAR-safe: iter s writes
// buf=s&1; all readers of that buf passed barrier s-1), syn in 4 accumulators
// (dependent-FMA chain 200 -> ~60 cyc), tanh via __expf.
// ---------------------------------------------------------------------------
__global__ __launch_bounds__(256) void steps_kernel(const float* __restrict__ cdt,
                                                    const int* __restrict__ idxT,
                                                    const float* __restrict__ vals2T,
                                                    const unsigned int* __restrict__ tbl,
                                                    float* __restrict__ out) {
    __shared__ float  a_sh[2][N_NEU];
    __shared__ float2 vals2_sh[(KN / 2) * N_NEU];   // 51200 B

    const int n = threadIdx.x;
    const int b = blockIdx.x;

    const float2* v2g = reinterpret_cast<const float2*>(vals2T);
    for (int i = n; i < (KN / 2) * N_NEU; i += 256) vals2_sh[i] = v2g[i];

    unsigned int idxp[13];
#pragma unroll
    for (int w = 0; w < 13; ++w) idxp[w] = 0u;
#pragma unroll
    for (int k = 0; k < KN; ++k) {
        const unsigned int ii = (unsigned int)idxT[k * N_NEU + n];
        idxp[k >> 2] |= ii << ((k & 3) * 8);
    }

    float x[D_DIM], ccdt[D_DIM];
    const float4* cp4 = reinterpret_cast<const float4*>(cdt + ((size_t)b * N_NEU + n) * D_DIM);
#pragma unroll
    for (int i = 0; i < 8; ++i) {
        const float4 cv = cp4[i];
        ccdt[4 * i + 0] = cv.x; ccdt[4 * i + 1] = cv.y;
        ccdt[4 * i + 2] = cv.z; ccdt[4 * i + 3] = cv.w;
    }
#pragma unroll
    for (int d = 0; d < D_DIM; ++d) x[d] = 0.f;

    const float K1 = 1.0f - DT * GAMMA;   // 0.995

    for (int s = 0; s < NSTEP; ++s) {
        float nrm2 = 1e-12f;
#pragma unroll
        for (int d = 0; d < D_DIM; ++d) nrm2 = fmaf(x[d], x[d], nrm2);
        // tanh(z) = 1 - 2/(exp(2z)+1), z >= 0
        const float z = sqrtf(nrm2);
        const float a = 1.0f - 2.0f / (__expf(2.0f * z) + 1.0f);

        const int buf = s & 1;
        a_sh[buf][n] = a;
        __syncthreads();            // a visible (also covers initial staging)

        float s0 = 0.f, s1 = 0.f, s2 = 0.f, s3 = 0.f;
#pragma unroll
        for (int k2 = 0; k2 < KN / 2; ++k2) {
            const float2 vv = vals2_sh[k2 * N_NEU + n];
            const int k0 = 2 * k2, k1 = 2 * k2 + 1;
            const int i0 = (int)((idxp[k0 >> 2] >> ((k0 & 3) * 8)) & 255u);
            const int i1 = (int)((idxp[k1 >> 2] >> ((k1 & 3) * 8)) & 255u);
            if (k2 & 1) { s2 = fmaf(a_sh[buf][i0], vv.x, s2); s3 = fmaf(a_sh[buf][i1], vv.y, s3); }
            else        { s0 = fmaf(a_sh[buf][i0], vv.x, s0); s1 = fmaf(a_sh[buf][i1], vv.y, s1); }
        }
        const float syn = (s0 + s1) + (s2 + s3);

        // x <- K1*x + ccdt (registers)
#pragma unroll
        for (int d = 0; d < D_DIM; ++d) x[d] = fmaf(K1, x[d], ccdt[d]);

        // sigma MLP via table lerp
        const float uu = fmaf(syn, TBL_IDL, -TBL_LO * TBL_IDL);
        int i = (int)floorf(uu);
        i = (i < 0) ? 0 : (i > TBL_K - 2 ? TBL_K - 2 : i);
        const float t = uu - (float)i;
        const uint4* rp = reinterpret_cast<const uint4*>(tbl + (size_t)i * 32);
#pragma unroll 2
        for (int c = 0; c < 8; ++c) {
            const uint4 q = rp[c];
            x[4 * c + 0] = fmaf(t, bf_hi(q.x), x[4 * c + 0] + bf_lo(q.x));
            x[4 * c + 1] = fmaf(t, bf_hi(q.y), x[4 * c + 1] + bf_lo(q.y));
            x[4 * c + 2] = fmaf(t, bf_hi(q.z), x[4 * c + 2] + bf_lo(q.z));
            x[4 * c + 3] = fmaf(t, bf_hi(q.w), x[4 * c + 3] + bf_lo(q.w));
        }
    }

    float4* op4 = reinterpret_cast<float4*>(out + ((size_t)b * N_NEU + n) * D_DIM);
#pragma unroll
    for (int i = 0; i < 8; ++i)
        op4[i] = make_float4(x[4 * i + 0], x[4 * i + 1], x[4 * i + 2], x[4 * i + 3]);
}

extern "C" void kernel_launch(void* const* d_in, const int* in_sizes, int n_in,
                              void* d_out, int out_size, void* d_ws, size_t ws_size,
                              hipStream_t stream) {
    const float* u        = (const float*)d_in[0];
    const float* features = (const float*)d_in[1];
    const float* bias     = (const float*)d_in[2];
    const float* w_in     = (const float*)d_in[3];
    const float* b_in     = (const float*)d_in[4];
    const float* sig_w1   = (const float*)d_in[5];
    const float* sig_b1   = (const float*)d_in[6];
    const float* sig_w2   = (const float*)d_in[7];
    const float* sig_b2   = (const float*)d_in[8];
    float* out = (float*)d_out;

    char*         ws     = (char*)d_ws;
    int*          idxT   = (int*)ws;                      // 51200 B
    float*        vals2T = (float*)(ws + 51200);          // 51200 B
    unsigned int* tbl    = (unsigned int*)(ws + 102400);  // 512 KiB
    float*        cdt    = (float*)(ws + 102400 + 524288);// 16 MiB

    hipLaunchKernelGGL(topk_kernel, dim3(N_NEU), dim3(256), 0, stream,
                       features, idxT, vals2T);
    hipLaunchKernelGGL(mlp_table_kernel, dim3(TBL_K * 32 / 256), dim3(256), 0, stream,
                       sig_w1, sig_b1, sig_w2, tbl);
    hipLaunchKernelGGL(uproj_mfma_kernel, dim3(B_SZ * N_NEU / 64), dim3(256), 0, stream,
                       u, w_in, b_in, bias, sig_b2, cdt);
    hipLaunchKernelGGL(steps_kernel, dim3(B_SZ), dim3(256), 0, stream,
                       cdt, idxT, vals2T, tbl, out);
}